// Round 3
// baseline (274.696 us; speedup 1.0000x reference)
//
#include <hip/hip_runtime.h>
#include <stdint.h>

#define CIN   256
#define COUT  128
#define HH    128
#define WW    128
#define NIMG  16

typedef unsigned long long u64;
typedef unsigned int u32;
typedef u32 u32x4 __attribute__((ext_vector_type(4)));

// ---------------------------------------------------------------------------
// Pack sign bits of x: px[(n*HH + h)*WW + w][word 0..3], bit (c&63) of word
// (c>>6) is (x[n][c][h][w] > 0). Position-major, 4 u64 per position.
// Memory-bound: reads 256 MiB fp32, writes 8 MiB packed. ~45 us measured.
// ---------------------------------------------------------------------------
__global__ __launch_bounds__(256) void pack_x_kernel(const float* __restrict__ x,
                                                     u64* __restrict__ px) {
    int t = blockIdx.x * 256 + threadIdx.x;   // position id: n*16384 + h*128 + w
    int w = t & (WW - 1);
    int h = (t >> 7) & (HH - 1);
    int n = t >> 14;
    const float* xp = x + (size_t)n * CIN * HH * WW + (size_t)h * WW + w;
    u64 words[4];
#pragma unroll
    for (int wd = 0; wd < 4; ++wd) {
        u64 acc = 0;
#pragma unroll 16
        for (int cc = 0; cc < 64; ++cc) {
            float v = xp[(size_t)(wd * 64 + cc) * (HH * WW)];
            acc |= (u64)(v > 0.0f) << cc;
        }
        words[wd] = acc;
    }
    ulonglong2* o = reinterpret_cast<ulonglong2*>(px + (size_t)t * 4);
    o[0] = make_ulonglong2(words[0], words[1]);
    o[1] = make_ulonglong2(words[2], words[3]);
}

// ---------------------------------------------------------------------------
// Pack weight sign bits + alpha. One block per co; thread = channel c.
// pw[co*36 + tap*4 + word], tap = kh*3+kw. alpha[co] = mean|W| over 2304.
// ---------------------------------------------------------------------------
__global__ __launch_bounds__(256) void pack_w_kernel(const float* __restrict__ wt,
                                                     u64* __restrict__ pw,
                                                     float* __restrict__ alpha) {
    int co = blockIdx.x;
    int c  = threadIdx.x;        // 0..255 = input channel
    int lane = c & 63;
    int word = c >> 6;
    const float* wp = wt + ((size_t)co * CIN + c) * 9;
    float vals[9];
    float asum = 0.0f;
#pragma unroll
    for (int k = 0; k < 9; ++k) { vals[k] = wp[k]; asum += fabsf(vals[k]); }
#pragma unroll
    for (int k = 0; k < 9; ++k) {
        u64 m = __ballot(vals[k] > 0.0f);
        if (lane == 0) pw[co * 36 + k * 4 + word] = m;
    }
    __shared__ float red[4];
    for (int off = 32; off > 0; off >>= 1) asum += __shfl_down(asum, off);
    if (lane == 0) red[word] = asum;
    __syncthreads();
    if (c == 0) alpha[co] = (red[0] + red[1] + red[2] + red[3]) * (1.0f / 2304.0f);
}

// ---------------------------------------------------------------------------
// XNOR conv v3. R1/R2 forensics: VGPR=52 both rounds => compiler sinks the
// px loads into the co-loop (empty-asm pins were a no-op; sinking read-only
// loads past __syncthreads is legal). Fix: load the 9 taps via inline-asm
// global_load_dwordx4 with "=&v" outputs + embedded vmcnt(0). Asm results
// are opaque/non-rematerializable: RA must keep the 72 input VGPRs live
// across the co-loop. Weights stay in LDS (uniform ds_read_b128 broadcast,
// 0 conflicts measured). Border taps masked on the popcount subtotal.
// out[n][co][h][w] = (256*nv - 2*mismatch) * alpha[w]   (alpha by WIDTH!)
// ---------------------------------------------------------------------------
__global__ __launch_bounds__(256, 4) void conv_kernel(const u64* __restrict__ px,
                                                      const u64* __restrict__ pw,
                                                      const float* __restrict__ alpha,
                                                      float* __restrict__ out) {
    __shared__ __align__(16) u64 wlds[COUT * 36];   // 36 KiB
    for (int i = threadIdx.x; i < COUT * 36; i += 256) wlds[i] = pw[i];

    int tid = threadIdx.x;
    int w  = tid & (WW - 1);
    int hh = tid >> 7;                 // 0/1: two rows per block
    int bid = blockIdx.x;              // 0..1023 = n*64 + hpair
    int h = ((bid & 63) << 1) | hh;
    int n = bid >> 6;

    int vmask[9];
    u32 voff[9];
    int nv = 0;
#pragma unroll
    for (int dh = -1; dh <= 1; ++dh) {
#pragma unroll
        for (int dw = -1; dw <= 1; ++dw) {
            int k = (dh + 1) * 3 + (dw + 1);
            int hn = h + dh, wn = w + dw;
            bool valid = (hn >= 0) && (hn < HH) && (wn >= 0) && (wn < WW);
            vmask[k] = valid ? -1 : 0;
            nv += valid ? 1 : 0;
            int hc = min(max(hn, 0), HH - 1);   // clamped: safe addr, data masked later
            int wc = min(max(wn, 0), WW - 1);
            voff[k] = (u32)(((n * HH + hc) * WW + wc) * 32);   // byte offset, < 8 MiB
        }
    }

    // Opaque tap loads: 2x dwordx4 per tap (32 B), saddr form, wait inside.
    u32x4 xa[9], xb[9];
    const u64* pxb = px;
#pragma unroll
    for (int k = 0; k < 9; ++k) {
        asm volatile(
            "global_load_dwordx4 %0, %2, %3\n\t"
            "global_load_dwordx4 %1, %2, %3 offset:16\n\t"
            "s_waitcnt vmcnt(0)"
            : "=&v"(xa[k]), "=&v"(xb[k])
            : "v"(voff[k]), "s"(pxb));
    }

    __syncthreads();   // LDS weight stage complete

    int base = nv << 8;                 // 256 * valid taps
    float aw = alpha[w];                // faithful broadcast: alpha[WIDTH]
    float* op = out + (size_t)n * COUT * HH * WW + (size_t)h * WW + w;
    const u32x4* wl = reinterpret_cast<const u32x4*>(wlds);

#pragma unroll 1
    for (int co = 0; co < COUT; ++co) {
        const u32x4* wp = wl + co * 18;     // 36 u64 = 18 u32x4 per co
        int M = 0;
#pragma unroll
        for (int k = 0; k < 9; ++k) {
            u32x4 wa = wp[2 * k];
            u32x4 wb = wp[2 * k + 1];
            int c;
            c  = __popc(xa[k].x ^ wa.x);
            c += __popc(xa[k].y ^ wa.y);
            c += __popc(xa[k].z ^ wa.z);
            c += __popc(xa[k].w ^ wa.w);
            c += __popc(xb[k].x ^ wb.x);
            c += __popc(xb[k].y ^ wb.y);
            c += __popc(xb[k].z ^ wb.z);
            c += __popc(xb[k].w ^ wb.w);
            M += c & vmask[k];          // zero out OOB taps
        }
        op[(size_t)co * (HH * WW)] = (float)(base - 2 * M) * aw;
    }
}

extern "C" void kernel_launch(void* const* d_in, const int* in_sizes, int n_in,
                              void* d_out, int out_size, void* d_ws, size_t ws_size,
                              hipStream_t stream) {
    const float* x  = (const float*)d_in[0];
    const float* wt = (const float*)d_in[1];
    float* out = (float*)d_out;

    char* ws = (char*)d_ws;
    const size_t PX_BYTES = (size_t)NIMG * HH * WW * 4 * sizeof(u64);  // 8 MiB
    const size_t PW_BYTES = (size_t)COUT * 36 * sizeof(u64);           // 36 KiB
    if (ws_size < PX_BYTES + PW_BYTES + 512) return;  // workspace too small
    u64*   px    = (u64*)ws;
    u64*   pw    = (u64*)(ws + PX_BYTES);
    float* alpha = (float*)(ws + PX_BYTES + PW_BYTES);

    pack_x_kernel<<<NIMG * HH * WW / 256, 256, 0, stream>>>(x, px);
    pack_w_kernel<<<COUT, 256, 0, stream>>>(wt, pw, alpha);
    conv_kernel<<<NIMG * (HH / 2), 256, 0, stream>>>(px, pw, alpha, out);
}

// Round 4
// 262.975 us; speedup vs baseline: 1.0446x; 1.0446x over previous
//
#include <hip/hip_runtime.h>
#include <stdint.h>

#define CIN   256
#define COUT  128
#define HH    128
#define WW    128
#define NIMG  16

typedef unsigned long long u64;
typedef unsigned int u32;
typedef u32 u32x4 __attribute__((ext_vector_type(4)));

// ---------------------------------------------------------------------------
// Pack sign bits of x: px[(n*HH + h)*WW + w][word 0..3], bit (c&63) of word
// (c>>6) is (x[n][c][h][w] > 0). Position-major, 4 u64 per position.
// ---------------------------------------------------------------------------
__global__ __launch_bounds__(256) void pack_x_kernel(const float* __restrict__ x,
                                                     u64* __restrict__ px) {
    int t = blockIdx.x * 256 + threadIdx.x;
    int w = t & (WW - 1);
    int h = (t >> 7) & (HH - 1);
    int n = t >> 14;
    const float* xp = x + (size_t)n * CIN * HH * WW + (size_t)h * WW + w;
    u64 words[4];
#pragma unroll
    for (int wd = 0; wd < 4; ++wd) {
        u64 acc = 0;
#pragma unroll 16
        for (int cc = 0; cc < 64; ++cc) {
            float v = xp[(size_t)(wd * 64 + cc) * (HH * WW)];
            acc |= (u64)(v > 0.0f) << cc;
        }
        words[wd] = acc;
    }
    ulonglong2* o = reinterpret_cast<ulonglong2*>(px + (size_t)t * 4);
    o[0] = make_ulonglong2(words[0], words[1]);
    o[1] = make_ulonglong2(words[2], words[3]);
}

// ---------------------------------------------------------------------------
// Pack weight sign bits, alpha, and the border-correction table.
// corrg[(pat*COUT + co)*2 + half] = sum over taps invalid in pattern `pat`
// of popcount of that tap's 128-bit half of w. pat = ht*3 + wt where
// ht/wt in {0=low-border,1=interior,2=high-border}.
// ---------------------------------------------------------------------------
__global__ __launch_bounds__(256) void pack_w_kernel(const float* __restrict__ wt,
                                                     u64* __restrict__ pw,
                                                     float* __restrict__ alpha,
                                                     unsigned short* __restrict__ corrg) {
    int co = blockIdx.x;
    int c  = threadIdx.x;        // 0..255 = input channel
    int lane = c & 63;
    int word = c >> 6;
    __shared__ u64 wsh[9][4];
    __shared__ u32 pct[9][2];
    __shared__ float red[4];
    const float* wp = wt + ((size_t)co * CIN + c) * 9;
    float vals[9];
    float asum = 0.0f;
#pragma unroll
    for (int k = 0; k < 9; ++k) { vals[k] = wp[k]; asum += fabsf(vals[k]); }
#pragma unroll
    for (int k = 0; k < 9; ++k) {
        u64 m = __ballot(vals[k] > 0.0f);
        if (lane == 0) { pw[co * 36 + k * 4 + word] = m; wsh[k][word] = m; }
    }
    for (int off = 32; off > 0; off >>= 1) asum += __shfl_down(asum, off);
    if (lane == 0) red[word] = asum;
    __syncthreads();
    if (c < 18) {
        int k = c >> 1, hf = c & 1;
        pct[k][hf] = __popcll(wsh[k][2 * hf]) + __popcll(wsh[k][2 * hf + 1]);
    }
    if (c == 0) alpha[co] = (red[0] + red[1] + red[2] + red[3]) * (1.0f / 2304.0f);
    __syncthreads();
    if (c < 18) {
        int pat = c >> 1, hf = c & 1;
        int ht = pat / 3, wtp = pat % 3;
        u32 corr = 0;
#pragma unroll
        for (int k = 0; k < 9; ++k) {
            int dh = k / 3 - 1, dw = k % 3 - 1;
            bool inv = (dh == -1 && ht == 0) || (dh == 1 && ht == 2) ||
                       (dw == -1 && wtp == 0) || (dw == 1 && wtp == 2);
            if (inv) corr += pct[k][hf];
        }
        corrg[(pat * COUT + co) * 2 + hf] = (unsigned short)corr;
    }
}

// ---------------------------------------------------------------------------
// XNOR conv v4. R1-R3 lesson: 72 live input VGPRs per thread always lose to
// the register allocator (loads sunk into loop, or AGPR-parked with
// accvgpr_read per use; VGPR_Count stuck at 52 all three rounds). Fix the
// PRESSURE, not the allocator: 2 threads per position, each owns one
// 128-channel half (9 x u32x4 = 36 VGPR inputs via one opaque asm block).
// Hot loop = single unmasked xor/popc chain per co (border garbage removed
// by precomputed per-pattern correction table in LDS) + shfl_xor(1) to
// combine halves; even lane stores co0=2i, odd lane stores co1=2i+1.
// Weights in LDS, 2-address broadcast ds_read_b128 (2-way = free, m136).
// out[n][co][h][w] = (256*nv - 2*mismatch) * alpha[w]   (alpha by WIDTH!)
// ---------------------------------------------------------------------------
__global__ __launch_bounds__(256, 3) void conv_kernel(const u64* __restrict__ px,
                                                      const u64* __restrict__ pw,
                                                      const float* __restrict__ alpha,
                                                      const unsigned short* __restrict__ corrg,
                                                      float* __restrict__ out) {
    __shared__ __align__(16) u64 wlds[COUT * 36];            // 36 KiB
    __shared__ unsigned short corrs[9 * COUT * 2];           // 4.5 KiB
    {
        const u32x4* s = reinterpret_cast<const u32x4*>(pw);
        u32x4* d = reinterpret_cast<u32x4*>(wlds);
        for (int i = threadIdx.x; i < COUT * 36 / 2; i += 256) d[i] = s[i];
        const u32* cs = reinterpret_cast<const u32*>(corrg);
        u32* cd = reinterpret_cast<u32*>(corrs);
        for (int i = threadIdx.x; i < 9 * COUT; i += 256) cd[i] = cs[i];
    }

    int tid  = threadIdx.x;
    int w    = tid >> 1;          // position within row
    int half = tid & 1;           // channel half: words {0,1} or {2,3}
    int bid  = blockIdx.x;        // n*128 + h
    int h = bid & (HH - 1);
    int n = bid >> 7;

    u32 off[9];
    u32 vm[9];
    int nv = 0;
#pragma unroll
    for (int dh = -1; dh <= 1; ++dh) {
#pragma unroll
        for (int dw = -1; dw <= 1; ++dw) {
            int k = (dh + 1) * 3 + (dw + 1);
            int hn = h + dh, wn = w + dw;
            bool valid = (hn >= 0) && (hn < HH) && (wn >= 0) && (wn < WW);
            vm[k] = valid ? 0xFFFFFFFFu : 0u;
            nv += valid ? 1 : 0;
            int hc = min(max(hn, 0), HH - 1);
            int wc = min(max(wn, 0), WW - 1);
            off[k] = (u32)((((n * HH + hc) * WW + wc) * 32) + half * 16);
        }
    }

    // One opaque asm block: 9x dwordx4 (my half of each tap), single wait.
    // Consumers data-depend on the block, so they can't be hoisted past it.
    u32x4 t0, t1, t2, t3, t4, t5, t6, t7, t8;
    asm volatile(
        "global_load_dwordx4 %0, %9, %18\n\t"
        "global_load_dwordx4 %1, %10, %18\n\t"
        "global_load_dwordx4 %2, %11, %18\n\t"
        "global_load_dwordx4 %3, %12, %18\n\t"
        "global_load_dwordx4 %4, %13, %18\n\t"
        "global_load_dwordx4 %5, %14, %18\n\t"
        "global_load_dwordx4 %6, %15, %18\n\t"
        "global_load_dwordx4 %7, %16, %18\n\t"
        "global_load_dwordx4 %8, %17, %18\n\t"
        "s_waitcnt vmcnt(0)"
        : "=&v"(t0), "=&v"(t1), "=&v"(t2), "=&v"(t3), "=&v"(t4),
          "=&v"(t5), "=&v"(t6), "=&v"(t7), "=&v"(t8)
        : "v"(off[0]), "v"(off[1]), "v"(off[2]), "v"(off[3]), "v"(off[4]),
          "v"(off[5]), "v"(off[6]), "v"(off[7]), "v"(off[8]), "s"(px));

    u32x4 xr[9] = {t0, t1, t2, t3, t4, t5, t6, t7, t8};
#pragma unroll
    for (int k = 0; k < 9; ++k) {
        u32x4 mv = {vm[k], vm[k], vm[k], vm[k]};
        xr[k] &= mv;             // zero OOB taps; corr table removes popc(w) garbage
    }

    __syncthreads();   // LDS stage complete

    int base = nv << 8;                     // 256 * valid taps
    float aw = alpha[w];                    // faithful broadcast: alpha[WIDTH]
    int ht  = (h == 0) ? 0 : ((h == HH - 1) ? 2 : 1);
    int wtp = (w == 0) ? 0 : ((w == WW - 1) ? 2 : 1);
    const unsigned short* corrP = &corrs[(ht * 3 + wtp) * COUT * 2 + half];
    const u32x4* wl = reinterpret_cast<const u32x4*>(wlds);  // 18 per co
    float* opb = out + ((size_t)(n * COUT + half) * HH + h) * WW + w;
    const size_t ostep = (size_t)2 * HH * WW;

#pragma unroll 2
    for (int i = 0; i < COUT / 2; ++i) {
        const u32x4* wpa = wl + (2 * i) * 18 + half;   // co0 = 2i, my half
        const u32x4* wpb = wpa + 18;                    // co1 = 2i+1
        int m0 = 0, m1 = 0;
#pragma unroll
        for (int k = 0; k < 9; ++k) {
            u32x4 wa = wpa[k * 2];
            u32x4 wb = wpb[k * 2];
            m0 += __popc(xr[k].x ^ wa.x) + __popc(xr[k].y ^ wa.y) +
                  __popc(xr[k].z ^ wa.z) + __popc(xr[k].w ^ wa.w);
            m1 += __popc(xr[k].x ^ wb.x) + __popc(xr[k].y ^ wb.y) +
                  __popc(xr[k].z ^ wb.z) + __popc(xr[k].w ^ wb.w);
        }
        m0 -= corrP[4 * i];          // border garbage for (co0, my half)
        m1 -= corrP[4 * i + 2];      // border garbage for (co1, my half)
        int send = half ? m0 : m1;   // even sends its co1-partial, odd its co0
        int recv = __shfl_xor(send, 1);
        int mine = half ? m1 : m0;   // even keeps co0, odd keeps co1
        int full = mine + recv;
        opb[(size_t)i * ostep] = (float)(base - 2 * full) * aw;
    }
}

extern "C" void kernel_launch(void* const* d_in, const int* in_sizes, int n_in,
                              void* d_out, int out_size, void* d_ws, size_t ws_size,
                              hipStream_t stream) {
    const float* x  = (const float*)d_in[0];
    const float* wt = (const float*)d_in[1];
    float* out = (float*)d_out;

    char* ws = (char*)d_ws;
    const size_t PX_BYTES   = (size_t)NIMG * HH * WW * 4 * sizeof(u64);  // 8 MiB
    const size_t PW_BYTES   = (size_t)COUT * 36 * sizeof(u64);           // 36 KiB
    const size_t AL_BYTES   = 512;
    const size_t CORR_BYTES = (size_t)9 * COUT * 2 * sizeof(unsigned short); // 4.5 KiB
    if (ws_size < PX_BYTES + PW_BYTES + AL_BYTES + CORR_BYTES) return;
    u64*   px    = (u64*)ws;
    u64*   pw    = (u64*)(ws + PX_BYTES);
    float* alpha = (float*)(ws + PX_BYTES + PW_BYTES);
    unsigned short* corrg = (unsigned short*)(ws + PX_BYTES + PW_BYTES + AL_BYTES);

    pack_x_kernel<<<NIMG * HH * WW / 256, 256, 0, stream>>>(x, px);
    pack_w_kernel<<<COUT, 256, 0, stream>>>(wt, pw, alpha, corrg);
    conv_kernel<<<NIMG * HH, 256, 0, stream>>>(px, pw, alpha, corrg, out);
}